// Round 2
// baseline (176.379 us; speedup 1.0000x reference)
//
#include <hip/hip_runtime.h>
#include <hip/hip_bf16.h>
#include <math.h>

// MultiEmbeddingSGNS: out[b] = sigmoid( dot( sum_i wt_i*T_i[x[b,i]],
//                                            sum_i wc_i*C_i[x[b,i]] ) )
// wt = softmax(tgt_w), wc = softmax(ctx_w), D=128, BS=16384, fp32.
//
// R2: 4 elements per wave. Lanes split 32/32; each half-wave covers one
// element's 128 dims via float4 (16 B/lane = 1 KB per load instruction).
// 12 KB in flight per wave (vs 3 KB in R1) to hide HBM gather latency.

#define D 128
#define WAVES_PER_BLOCK 4
#define ELEMS_PER_WAVE 4

__global__ __launch_bounds__(64 * WAVES_PER_BLOCK)
void sgns_kernel(const int* __restrict__ x,
                 const float* __restrict__ tgt_base,
                 const float* __restrict__ tgt_a,
                 const float* __restrict__ tgt_b,
                 const float* __restrict__ ctx_base,
                 const float* __restrict__ ctx_a,
                 const float* __restrict__ ctx_b,
                 const float* __restrict__ tgt_w,
                 const float* __restrict__ ctx_w,
                 float* __restrict__ out,
                 int bs) {
    const int wave = threadIdx.x >> 6;
    const int lane = threadIdx.x & 63;
    const int half = lane >> 5;   // which element of the pair
    const int sub  = lane & 31;   // float4 slot within the row (32*16B = 512B)
    const int b0 = (blockIdx.x * WAVES_PER_BLOCK + wave) * ELEMS_PER_WAVE;
    if (b0 >= bs) return;

    // ---- index loads for both pairs first (hide latency) ----
    int j0[2], j1[2], j2[2], bsel[2];
    #pragma unroll
    for (int p = 0; p < 2; ++p) {
        int b = b0 + 2 * p + half;
        bsel[p] = b;
        b = b < bs ? b : bs - 1;  // clamp (bs % 4 == 0 normally; safety)
        const int* xp = x + (size_t)b * 3;
        j0[p] = xp[0];
        j1[p] = xp[1];
        j2[p] = xp[2];
    }

    // ---- row loads: 12 x float4 (1 KB each across the wave) ----
    float4 T0[2], T1[2], T2[2], C0[2], C1[2], C2[2];
    #pragma unroll
    for (int p = 0; p < 2; ++p) {
        const size_t off = (size_t)sub * 4;
        T0[p] = *(const float4*)(tgt_base + (size_t)j0[p] * D + off);
        T1[p] = *(const float4*)(tgt_a    + (size_t)j1[p] * D + off);
        T2[p] = *(const float4*)(tgt_b    + (size_t)j2[p] * D + off);
        C0[p] = *(const float4*)(ctx_base + (size_t)j0[p] * D + off);
        C1[p] = *(const float4*)(ctx_a    + (size_t)j1[p] * D + off);
        C2[p] = *(const float4*)(ctx_b    + (size_t)j2[p] * D + off);
    }

    // ---- softmax of the two 3-element weight vectors (wave-uniform) ----
    float t0 = tgt_w[0], t1 = tgt_w[1], t2 = tgt_w[2];
    float tm = fmaxf(t0, fmaxf(t1, t2));
    float te0 = __expf(t0 - tm), te1 = __expf(t1 - tm), te2 = __expf(t2 - tm);
    float tinv = 1.0f / (te0 + te1 + te2);
    float wt0 = te0 * tinv, wt1 = te1 * tinv, wt2 = te2 * tinv;

    float c0 = ctx_w[0], c1 = ctx_w[1], c2 = ctx_w[2];
    float cm = fmaxf(c0, fmaxf(c1, c2));
    float ce0 = __expf(c0 - cm), ce1 = __expf(c1 - cm), ce2 = __expf(c2 - cm);
    float cinv = 1.0f / (ce0 + ce1 + ce2);
    float wc0 = ce0 * cinv, wc1 = ce1 * cinv, wc2 = ce2 * cinv;

    // ---- blend + dot + segmented (width-32) reduction + store ----
    #pragma unroll
    for (int p = 0; p < 2; ++p) {
        float tx = wt0 * T0[p].x + wt1 * T1[p].x + wt2 * T2[p].x;
        float ty = wt0 * T0[p].y + wt1 * T1[p].y + wt2 * T2[p].y;
        float tz = wt0 * T0[p].z + wt1 * T1[p].z + wt2 * T2[p].z;
        float tw = wt0 * T0[p].w + wt1 * T1[p].w + wt2 * T2[p].w;

        float cx = wc0 * C0[p].x + wc1 * C1[p].x + wc2 * C2[p].x;
        float cy = wc0 * C0[p].y + wc1 * C1[p].y + wc2 * C2[p].y;
        float cz = wc0 * C0[p].z + wc1 * C1[p].z + wc2 * C2[p].z;
        float cw = wc0 * C0[p].w + wc1 * C1[p].w + wc2 * C2[p].w;

        float d = tx * cx + ty * cy + tz * cz + tw * cw;

        #pragma unroll
        for (int off = 16; off > 0; off >>= 1)
            d += __shfl_down(d, off, 32);

        if (sub == 0 && bsel[p] < bs)
            out[bsel[p]] = 1.0f / (1.0f + __expf(-d));
    }
}

extern "C" void kernel_launch(void* const* d_in, const int* in_sizes, int n_in,
                              void* d_out, int out_size, void* d_ws, size_t ws_size,
                              hipStream_t stream) {
    const int*   x        = (const int*)  d_in[0];
    const float* tgt_base = (const float*)d_in[1];
    const float* tgt_a    = (const float*)d_in[2];
    const float* tgt_b    = (const float*)d_in[3];
    const float* ctx_base = (const float*)d_in[4];
    const float* ctx_a    = (const float*)d_in[5];
    const float* ctx_b    = (const float*)d_in[6];
    const float* tgt_w    = (const float*)d_in[7];
    const float* ctx_w    = (const float*)d_in[8];
    float* out = (float*)d_out;

    const int bs = out_size;  // 16384
    const int elems_per_block = WAVES_PER_BLOCK * ELEMS_PER_WAVE;  // 16
    const int block = 64 * WAVES_PER_BLOCK;
    const int grid = (bs + elems_per_block - 1) / elems_per_block;

    sgns_kernel<<<grid, block, 0, stream>>>(x, tgt_base, tgt_a, tgt_b,
                                            ctx_base, ctx_a, ctx_b,
                                            tgt_w, ctx_w, out, bs);
}